// Round 2
// baseline (103.864 us; speedup 1.0000x reference)
//
#include <hip/hip_runtime.h>
#include <hip/hip_bf16.h>
#include <stdint.h>

// AttentionHead: x[8,2048,1024](f32) @ {Wq,Wk,Wv}[1024,64](f32) + bias -> flash attn -> out[8,2048,64](f32)
// Inputs/outputs f32 per reference dtypes; internal q/k/vT scratch bf16; f32 accumulation.

typedef __attribute__((ext_vector_type(8))) short short8;   // 8 bf16 = 4 VGPRs (MFMA A/B frag)
typedef __attribute__((ext_vector_type(4))) short short4v;  // 8B packed store
typedef __attribute__((ext_vector_type(4))) float floatx4;  // MFMA C/D frag / 16B f32 load-store

static constexpr int Tn = 2048, En = 1024, Hn = 64;
static constexpr float kLog2e = 1.44269504088896340736f;

static __device__ __forceinline__ ushort f2bf(float f) {
  uint32_t u = __builtin_bit_cast(uint32_t, f);
  u += 0x7FFFu + ((u >> 16) & 1u);          // round-to-nearest-even
  return (ushort)(u >> 16);
}

// ---------------------------------------------------------------------------
// Kernel 0: pack Wq|Wk|Wv (f32) into bf16 B-fragment order.
// wpack[kstep][ntile][lane][8]: element = W[mat][kstep*32 + (lane>>4)*8 + j][(ntile&3)*16 + (lane&15)]
__global__ __launch_bounds__(64) void k_packw(const float* __restrict__ Wq,
                                              const float* __restrict__ Wk,
                                              const float* __restrict__ Wv,
                                              ushort* __restrict__ wpack) {
  int blk = blockIdx.x;
  int kstep = blk / 12, ntile = blk % 12;
  int l = threadIdx.x;
  const float* W = (ntile < 4) ? Wq : (ntile < 8) ? Wk : Wv;
  int col = (ntile & 3) * 16 + (l & 15);
  int k0 = kstep * 32 + (l >> 4) * 8;
  short8 v;
#pragma unroll
  for (int j = 0; j < 8; ++j) v[j] = (short)f2bf(W[(k0 + j) * Hn + col]);
  *reinterpret_cast<short8*>(wpack + ((size_t)(kstep * 12 + ntile) * 64 + l) * 8) = v;
}

// ---------------------------------------------------------------------------
// Kernel 1: QKV projection. 256 blocks x 256 thr (4 waves); wave = 16 rows x 192 cols.
// x (f32) read exactly once from HBM, converted to bf16 frags in-register.
// Writes q,k row-major bf16 [16384][64]; v transposed bf16 vT[b][64][2048].
__global__ __launch_bounds__(256) void k_qkv(const float* __restrict__ x,
                                             const ushort* __restrict__ wpack,
                                             const float* __restrict__ bq,
                                             const float* __restrict__ bk,
                                             const float* __restrict__ bv,
                                             ushort* __restrict__ q,
                                             ushort* __restrict__ k,
                                             ushort* __restrict__ vT) {
  int l = threadIdx.x & 63;
  int w = threadIdx.x >> 6;                       // wave 0..3
  int row0 = blockIdx.x * 64 + w * 16;            // this wave's 16 rows
  int lq = l & 15, g = l >> 4;
  const float* xrow = x + (size_t)(row0 + lq) * En + g * 8;
  const ushort* wp = wpack + (size_t)l * 8;
  floatx4 acc[12];
#pragma unroll
  for (int n = 0; n < 12; ++n) acc[n] = (floatx4){0.f, 0.f, 0.f, 0.f};

  for (int ks = 0; ks < 32; ++ks) {
    floatx4 f0 = *reinterpret_cast<const floatx4*>(xrow + ks * 32);
    floatx4 f1 = *reinterpret_cast<const floatx4*>(xrow + ks * 32 + 4);
    short8 af;
#pragma unroll
    for (int j = 0; j < 4; ++j) { af[j] = (short)f2bf(f0[j]); af[4 + j] = (short)f2bf(f1[j]); }
#pragma unroll
    for (int n = 0; n < 12; ++n) {
      short8 bf = *reinterpret_cast<const short8*>(wp + (size_t)(ks * 12 + n) * 512);
      acc[n] = __builtin_amdgcn_mfma_f32_16x16x32_bf16(af, bf, acc[n], 0, 0, 0);
    }
  }
  // epilogue: C/D frag is col = lane&15, row = (lane>>4)*4 + r
  int b = row0 >> 11;
  int tloc0 = (row0 & (Tn - 1)) + g * 4;
#pragma unroll
  for (int n = 0; n < 12; ++n) {
    int mat = n >> 2;
    int h = (n & 3) * 16 + lq;
    const float* bias = (mat == 0) ? bq : (mat == 1) ? bk : bv;
    float bias_f = bias[h];
    if (mat < 2) {
      ushort* dst = (mat == 0) ? q : k;
#pragma unroll
      for (int r = 0; r < 4; ++r)
        dst[(size_t)(row0 + g * 4 + r) * Hn + h] = f2bf(acc[n][r] + bias_f);
    } else {
      short4v pk;
#pragma unroll
      for (int r = 0; r < 4; ++r) pk[r] = (short)f2bf(acc[n][r] + bias_f);
      *reinterpret_cast<short4v*>(vT + ((size_t)b * Hn + h) * Tn + tloc0) = pk;
    }
  }
}

// ---------------------------------------------------------------------------
// Kernel 2: flash attention, transposed orientation.
//  S^T = mfma(A=K, B=Q^T): lane holds q = lane&15 (col), kv = (lane>>4)*4+r (row) -> softmax row in-lane.
//  out^T = mfma(A=V^T, B=P^T): col = q = lane&15 -> m/l/rescale all in-lane.
// 256 blocks x 512 thr: 8 waves = 4 q-tiles x 2-way KV split (merged via LDS).
__global__ __launch_bounds__(512) void k_attn(const ushort* __restrict__ qm,
                                              const ushort* __restrict__ km,
                                              const ushort* __restrict__ vT,
                                              const int* __restrict__ mask,
                                              float* __restrict__ out) {
  __shared__ ushort P[8][16 * 72];     // per-wave P[q][kv], pad 64->72
  __shared__ float accS[4][64][20];    // combine: per-lane 16 f32 + pad 4
  __shared__ float mS[4][64], lS[4][64];

  int tid = threadIdx.x;
  int l = tid & 63, w = tid >> 6;      // wave 0..7
  int qt = w & 3, half = w >> 2;
  int bid = blockIdx.x;
  int b = bid >> 5;                    // 32 blocks per batch
  int q0 = (bid & 31) * 64 + qt * 16;
  int lq = l & 15, g = l >> 4;

  const ushort* qbase = qm + ((size_t)(b * Tn + q0 + lq)) * Hn + g * 8;
  short8 qf0 = *reinterpret_cast<const short8*>(qbase);
  short8 qf1 = *reinterpret_cast<const short8*>(qbase + 32);

  const ushort* kbase = km + ((size_t)(b * Tn) + lq) * Hn + g * 8;
  const ushort* vbase = vT + ((size_t)b * Hn + lq) * Tn + g * 8;
  const int* mbase = mask + b * Tn + l;
  ushort* Pw = &P[w][0];

  float m = -1e30f, lsum = 0.f;
  floatx4 acc[4];
#pragma unroll
  for (int mt = 0; mt < 4; ++mt) acc[mt] = (floatx4){0.f, 0.f, 0.f, 0.f};

  for (int it = 0; it < 16; ++it) {
    const int kv0 = half * 1024 + it * 64;
    // ---- QK^T (S^T) ----
    floatx4 st[4];
#pragma unroll
    for (int t = 0; t < 4; ++t) {
      const ushort* kp = kbase + (size_t)(kv0 + t * 16) * Hn;
      short8 kf0 = *reinterpret_cast<const short8*>(kp);
      short8 kf1 = *reinterpret_cast<const short8*>(kp + 32);
      floatx4 z = (floatx4){0.f, 0.f, 0.f, 0.f};
      z = __builtin_amdgcn_mfma_f32_16x16x32_bf16(kf0, qf0, z, 0, 0, 0);
      z = __builtin_amdgcn_mfma_f32_16x16x32_bf16(kf1, qf1, z, 0, 0, 0);
      st[t] = z;
    }
    // ---- mask + online softmax (row in-lane: 16 values + 2 shuffles) ----
    unsigned long long bal = __ballot(mbase[kv0] != 0);
    float s[4][4];
    float tmax = -1e30f;
#pragma unroll
    for (int t = 0; t < 4; ++t)
#pragma unroll
      for (int r = 0; r < 4; ++r) {
        float sv = st[t][r] * 0.125f;
        int kvloc = t * 16 + g * 4 + r;
        if (!((bal >> kvloc) & 1ull)) sv = -1e9f;
        s[t][r] = sv;
        tmax = fmaxf(tmax, sv);
      }
    tmax = fmaxf(tmax, __shfl_xor(tmax, 16));
    tmax = fmaxf(tmax, __shfl_xor(tmax, 32));
    float mnew = fmaxf(m, tmax);
    float alpha = exp2f((m - mnew) * kLog2e);
    float ts = 0.f;
#pragma unroll
    for (int t = 0; t < 4; ++t) {
      short4v pk;
#pragma unroll
      for (int r = 0; r < 4; ++r) {
        float p = exp2f((s[t][r] - mnew) * kLog2e);
        ts += p;
        pk[r] = (short)f2bf(p);
      }
      *reinterpret_cast<short4v*>(Pw + lq * 72 + t * 16 + g * 4) = pk;
    }
    ts += __shfl_xor(ts, 16);
    ts += __shfl_xor(ts, 32);
    lsum = lsum * alpha + ts;
    m = mnew;
#pragma unroll
    for (int mt = 0; mt < 4; ++mt) acc[mt] *= alpha;
    __syncthreads();
    // ---- PV (out^T += V^T @ P^T) ----
    short8 pf0 = *reinterpret_cast<const short8*>(Pw + lq * 72 + g * 8);
    short8 pf1 = *reinterpret_cast<const short8*>(Pw + lq * 72 + 32 + g * 8);
#pragma unroll
    for (int mt = 0; mt < 4; ++mt) {
      const ushort* vp = vbase + (size_t)mt * 16 * Tn + kv0;
      short8 vf0 = *reinterpret_cast<const short8*>(vp);
      short8 vf1 = *reinterpret_cast<const short8*>(vp + 32);
      acc[mt] = __builtin_amdgcn_mfma_f32_16x16x32_bf16(vf0, pf0, acc[mt], 0, 0, 0);
      acc[mt] = __builtin_amdgcn_mfma_f32_16x16x32_bf16(vf1, pf1, acc[mt], 0, 0, 0);
    }
    __syncthreads();
  }

  // ---- merge the two KV halves (waves w and w+4 share q-tile) ----
  if (w >= 4) {
#pragma unroll
    for (int mt = 0; mt < 4; ++mt)
      *reinterpret_cast<floatx4*>(&accS[qt][l][mt * 4]) = acc[mt];
    mS[qt][l] = m;
    lS[qt][l] = lsum;
  }
  __syncthreads();
  if (w < 4) {
    float mo = mS[qt][l], lo = lS[qt][l];
    float mtot = fmaxf(m, mo);
    float ea = exp2f((m - mtot) * kLog2e);
    float eb = exp2f((mo - mtot) * kLog2e);
    float inv = 1.0f / (lsum * ea + lo * eb);
    float* obase = out + ((size_t)(b * Tn + q0 + lq)) * Hn;
#pragma unroll
    for (int mt = 0; mt < 4; ++mt) {
      const float* as = &accS[qt][l][mt * 4];
      floatx4 res;
#pragma unroll
      for (int r = 0; r < 4; ++r)
        res[r] = (acc[mt][r] * ea + as[r] * eb) * inv;
      *reinterpret_cast<floatx4*>(obase + mt * 16 + g * 4) = res;
    }
  }
}

// ---------------------------------------------------------------------------
extern "C" void kernel_launch(void* const* d_in, const int* in_sizes, int n_in,
                              void* d_out, int out_size, void* d_ws, size_t ws_size,
                              hipStream_t stream) {
  const float* x  = (const float*)d_in[0];
  const float* Wq = (const float*)d_in[1];
  const float* bq = (const float*)d_in[2];
  const float* Wk = (const float*)d_in[3];
  const float* bk = (const float*)d_in[4];
  const float* Wv = (const float*)d_in[5];
  const float* bv = (const float*)d_in[6];
  const int* mask = (const int*)d_in[7];
  float* outp = (float*)d_out;

  ushort* wpack = (ushort*)d_ws;                       // 32*12*64*8 = 196608 halves (384 KB)
  ushort* qbuf  = wpack + 196608;                      // 16384*64 bf16 (2 MB)
  ushort* kbuf  = qbuf + (size_t)16384 * 64;           // 2 MB
  ushort* vTbuf = kbuf + (size_t)16384 * 64;           // [8][64][2048] bf16 (2 MB)

  hipLaunchKernelGGL(k_packw, dim3(384), dim3(64), 0, stream, Wq, Wk, Wv, wpack);
  hipLaunchKernelGGL(k_qkv, dim3(256), dim3(256), 0, stream, x, wpack, bq, bk, bv,
                     qbuf, kbuf, vTbuf);
  hipLaunchKernelGGL(k_attn, dim3(256), dim3(512), 0, stream, qbuf, kbuf, vTbuf, mask, outp);
}